// Round 1
// baseline (1030.445 us; speedup 1.0000x reference)
//
#include <hip/hip_runtime.h>
#include <cmath>

#define BATCH 8
#define CH    3
#define HH    512
#define WW    512
#define NSLOT 7          // 6 subbands + final gaussian
#define MAXKS 117
#define MAXP  58

struct Weights { float w[MAXKS]; };

__device__ __forceinline__ int refl(int i, int n) {
    // numpy 'reflect' (no edge repeat); valid for |overhang| < n (p<=58 << 512)
    i = i < 0 ? -i : i;
    return i >= n ? 2 * n - 2 - i : i;
}

// Horizontal pass: img(b,c,y,:) -> out slot 0 (scratch). One block = 256 x's of one row.
__global__ __launch_bounds__(256) void hpass_kernel(
    const float* __restrict__ img, float* __restrict__ out,
    Weights wts, int ks, int p)
{
    __shared__ float smem[256 + 2 * MAXP];
    const int tid = threadIdx.x;
    const int x0  = blockIdx.x * 256;
    const int y   = blockIdx.y;
    const int bc  = blockIdx.z;
    const int b = bc / CH, c = bc % CH;

    const float* row = img + ((size_t)bc * HH + y) * WW;
    const int total = 256 + 2 * p;
    for (int i = tid; i < total; i += 256)
        smem[i] = row[refl(x0 - p + i, WW)];
    __syncthreads();

    float acc = 0.f;
    for (int t = 0; t < ks; ++t)
        acc += wts.w[t] * smem[tid + t];

    float* orow = out + (((size_t)(b * NSLOT + 0) * CH + c) * HH + y) * WW;
    orow[x0 + tid] = acc;
}

// Vertical pass: out slot 0 (h-blurred) -> out slot `slot`. Coalesced along x per tap.
__global__ __launch_bounds__(256) void vpass_kernel(
    float* __restrict__ out, int slot, Weights wts, int ks, int p)
{
    const int x  = blockIdx.x * 256 + threadIdx.x;
    const int y  = blockIdx.y;
    const int bc = blockIdx.z;
    const int b = bc / CH, c = bc % CH;

    const float* in = out + ((size_t)(b * NSLOT + 0) * CH + c) * (size_t)HH * WW;
    float acc = 0.f;
    for (int t = 0; t < ks; ++t) {
        const int yi = refl(y + t - p, HH);
        acc += wts.w[t] * in[(size_t)yi * WW + x];
    }
    out[(((size_t)(b * NSLOT + slot) * CH + c) * HH + y) * WW + x] = acc;
}

// In-place DoG: out[s] = g[s+1]-g[s] (g0=img), out[6] stays g6. One thread per pixel.
__global__ __launch_bounds__(256) void diff_kernel(
    const float* __restrict__ img, float* __restrict__ out)
{
    const size_t CHW = (size_t)CH * HH * WW;
    size_t idx = (size_t)blockIdx.x * 256 + threadIdx.x;
    if (idx >= (size_t)BATCH * CHW) return;
    const size_t b = idx / CHW, rem = idx - b * CHW;

    float prev = img[idx];
    float* obase = out + b * (size_t)NSLOT * CHW;
    float g[6];
#pragma unroll
    for (int s = 0; s < 6; ++s) g[s] = obase[(size_t)(s + 1) * CHW + rem];
    obase[rem] = g[0] - prev;
#pragma unroll
    for (int s = 1; s < 6; ++s) obase[(size_t)s * CHW + rem] = g[s] - g[s - 1];
    // slot 6 already holds g6 from vpass
}

extern "C" void kernel_launch(void* const* d_in, const int* in_sizes, int n_in,
                              void* d_out, int out_size, void* d_ws, size_t ws_size,
                              hipStream_t stream) {
    const float* img = (const float*)d_in[0];
    float* out = (float*)d_out;

    const double sigmas[6] = {0.6, 1.2, 2.4, 4.8, 9.6, 19.2};
    dim3 block(256);

    for (int i = 0; i < 6; ++i) {
        const double sig = sigmas[i];
        int ks = 2 * (int)std::ceil(3.0 * sig) + 1;
        if (ks < 7) ks = 7;
        const int p = ks / 2;

        Weights wts;
        double sum = 0.0;
        for (int t = 0; t < ks; ++t) {
            const double ax = (double)(t - p);
            const double v = std::exp(-(ax * ax) / (2.0 * sig * sig));
            wts.w[t] = (float)v;
            sum += v;
        }
        const float inv = (float)(1.0 / sum);
        for (int t = 0; t < ks; ++t) wts.w[t] *= inv;
        for (int t = ks; t < MAXKS; ++t) wts.w[t] = 0.f;

        dim3 grid(WW / 256, HH, BATCH * CH);
        hipLaunchKernelGGL(hpass_kernel, grid, block, 0, stream, img, out, wts, ks, p);
        hipLaunchKernelGGL(vpass_kernel, grid, block, 0, stream, out, i + 1, wts, ks, p);
    }

    const size_t N = (size_t)BATCH * CH * HH * WW;
    dim3 gridd((unsigned)((N + 255) / 256));
    hipLaunchKernelGGL(diff_kernel, gridd, block, 0, stream, img, out);
}

// Round 2
// 391.291 us; speedup vs baseline: 2.6334x; 2.6334x over previous
//
#include <hip/hip_runtime.h>
#include <cmath>
#include <cstddef>

#define BATCH 8
#define CH    3
#define HH    512
#define WW    512
#define NSLOT 7
#define HWX   (HH*WW)
#define NPIX  ((size_t)BATCH*CH*HH*WW)   // floats in one (B,C,H,W) volume
#define HALO  58
#define RSTR  640                         // padded LDS row stride (floats), 16B-aligned
#define NWP   289

// scales: KS {7,9,17,31,59,117}, P = KS/2, padded weight offsets WOP {7,21,37,61,99,165}
// layout: 7 zeros, then per scale [KS weights][7 zeros]

struct WP { float w[NWP]; };

__device__ __forceinline__ int refl(int i, int n) {
    i = i < 0 ? -i : i;
    return i >= n ? 2 * n - 2 - i : i;
}

// ---------------- horizontal blur: 4 consecutive px per thread, b128 sliding window ---------
template<int KS, int PD, int WOP>
__device__ __forceinline__ float4 hblur4(const float* __restrict__ lrow, int xt, const WP& wp)
{
    constexpr int D  = HALO - PD;     // window start offset within padded row
    constexpr int E  = D & 3;
    constexpr int C0 = D >> 2;
    constexpr int NT = (KS + 3) & ~3; // t padded to mult of 4 (weights zero-padded)
    const float4* l4 = (const float4*)lrow;
    float cb[16];
    {
        float4 t0 = l4[xt + C0 + 0];
        cb[0]=t0.x; cb[1]=t0.y; cb[2]=t0.z; cb[3]=t0.w;
        float4 t1 = l4[xt + C0 + 1];
        cb[4]=t1.x; cb[5]=t1.y; cb[6]=t1.z; cb[7]=t1.w;
    }
    float a[4] = {0.f, 0.f, 0.f, 0.f};
#pragma unroll
    for (int tb = 0; tb < NT; tb += 4) {
        const int ls = ((tb >> 2) + 2) & 3;
        float4 tn = l4[xt + C0 + (tb >> 2) + 2];
        cb[ls*4+0]=tn.x; cb[ls*4+1]=tn.y; cb[ls*4+2]=tn.z; cb[ls*4+3]=tn.w;
#pragma unroll
        for (int tt = 0; tt < 4; ++tt) {
            const float wt = wp.w[WOP + tb + tt];
#pragma unroll
            for (int j = 0; j < 4; ++j) {
                const int q    = E + tt + j;                    // 0..9
                const int slot = ((tb >> 2) + (q >> 2)) & 3;
                a[j] = fmaf(wt, cb[slot*4 + (q & 3)], a[j]);
            }
        }
    }
    return make_float4(a[0], a[1], a[2], a[3]);
}

// ---------------- vertical blur: 8 rows x float4 per thread, register sliding ----------------
template<int KS, int PD, int WOP>
__device__ __forceinline__ void vblur8(const float4* __restrict__ src, int xt, int y0,
                                       const WP& wp, float4* acc)
{
#pragma unroll
    for (int j = 0; j < 8; ++j) acc[j] = make_float4(0.f, 0.f, 0.f, 0.f);
#pragma unroll 2
    for (int t = 0; t < KS + 7; ++t) {
        const int yi = refl(y0 - PD + t, HH);
        const float4 v = src[(size_t)yi * (WW/4) + xt];
#pragma unroll
        for (int j = 0; j < 8; ++j) {
            const float wt = wp.w[WOP + t - j];    // zero-padded both sides
            acc[j].x = fmaf(wt, v.x, acc[j].x);
            acc[j].y = fmaf(wt, v.y, acc[j].y);
            acc[j].z = fmaf(wt, v.z, acc[j].z);
            acc[j].w = fmaf(wt, v.w, acc[j].w);
        }
    }
}

// ---------------- fused hpass, all 6 scales -> 6 contiguous ws volumes ----------------------
__global__ __launch_bounds__(256) void hpass6_kernel(const float* __restrict__ img,
                                                     float* __restrict__ ws, WP wp)
{
    __shared__ __align__(16) float lds[2][RSTR];
    const int xt = threadIdx.x;                  // 0..127
    const int r  = threadIdx.y;                  // 0..1
    const int y  = blockIdx.y * 2 + r;
    const int bc = blockIdx.z;
    const float* row = img + ((size_t)bc * HH + y) * WW;
    for (int i = xt; i < RSTR; i += 128)
        lds[r][i] = row[refl(i - HALO, WW)];
    __syncthreads();
    const size_t obase = ((size_t)bc * HH + y) * WW + 4 * xt;
    float4 o;
    o = hblur4<  7,  3,   7>(lds[r], xt, wp); *(float4*)(ws + 0*NPIX + obase) = o;
    o = hblur4<  9,  4,  21>(lds[r], xt, wp); *(float4*)(ws + 1*NPIX + obase) = o;
    o = hblur4< 17,  8,  37>(lds[r], xt, wp); *(float4*)(ws + 2*NPIX + obase) = o;
    o = hblur4< 31, 15,  61>(lds[r], xt, wp); *(float4*)(ws + 3*NPIX + obase) = o;
    o = hblur4< 59, 29,  99>(lds[r], xt, wp); *(float4*)(ws + 4*NPIX + obase) = o;
    o = hblur4<117, 58, 165>(lds[r], xt, wp); *(float4*)(ws + 5*NPIX + obase) = o;
}

// ---------------- single-scale hpass (fallback paths) ---------------------------------------
template<int KS, int PD, int WOP>
__global__ __launch_bounds__(256) void hpass1_kernel(const float* __restrict__ img,
                                                     float* dst, int dslot, WP wp)
{
    __shared__ __align__(16) float lds[2][RSTR];
    const int xt = threadIdx.x;
    const int r  = threadIdx.y;
    const int y  = blockIdx.y * 2 + r;
    const int bc = blockIdx.z;
    const int b = bc / CH, c = bc - b * CH;
    const float* row = img + ((size_t)bc * HH + y) * WW;
    for (int i = xt; i < RSTR; i += 128)
        lds[r][i] = row[refl(i - HALO, WW)];
    __syncthreads();
    const size_t vol = (dslot < 0) ? (size_t)bc * HWX
                                   : ((size_t)((b * NSLOT + dslot) * CH) + c) * HWX;
    float4 o = hblur4<KS, PD, WOP>(lds[r], xt, wp);
    *(float4*)(dst + vol + (size_t)y * WW + 4 * xt) = o;
}

// ---------------- per-scale vblur + diff step ------------------------------------------------
template<int KS, int PD, int WOP>
__device__ __forceinline__ void scale_step(const float4* h4, float4* od, int xt, int y0,
                                           const WP& wp, float4* gprev)
{
    float4 acc[8];
    vblur8<KS, PD, WOP>(h4, xt, y0, wp, acc);
#pragma unroll
    for (int j = 0; j < 8; ++j) {
        float4 g = acc[j], pv = gprev[j];
        od[(size_t)(y0 + j) * (WW/4) + xt] = make_float4(g.x - pv.x, g.y - pv.y,
                                                         g.z - pv.z, g.w - pv.w);
        gprev[j] = g;
    }
}

// ---------------- fused vpass+diff, all 6 scales --------------------------------------------
__global__ __launch_bounds__(128, 3) void vdiff6_kernel(const float* __restrict__ ws,
                                                        const float* __restrict__ img,
                                                        float* __restrict__ out, WP wp)
{
    const int xt = threadIdx.x;                 // 0..127
    const int y0 = blockIdx.y * 8;
    const int bc = blockIdx.z;
    const int b = bc / CH, c = bc - b * CH;
    const float4* img4 = (const float4*)img + (size_t)bc * (HWX/4);
    float4 gprev[8];
#pragma unroll
    for (int j = 0; j < 8; ++j) gprev[j] = img4[(size_t)(y0 + j) * (WW/4) + xt];
    float4* out4 = (float4*)out;
    const size_t hstep = (size_t)(BATCH * CH) * (HWX/4);
    const float4* h4 = (const float4*)ws + (size_t)bc * (HWX/4);
#define OSL(s) (out4 + ((size_t)((b * NSLOT + (s)) * CH) + c) * (HWX/4))
    scale_step<  7,  3,   7>(h4 + 0*hstep, OSL(0), xt, y0, wp, gprev);
    scale_step<  9,  4,  21>(h4 + 1*hstep, OSL(1), xt, y0, wp, gprev);
    scale_step< 17,  8,  37>(h4 + 2*hstep, OSL(2), xt, y0, wp, gprev);
    scale_step< 31, 15,  61>(h4 + 3*hstep, OSL(3), xt, y0, wp, gprev);
    scale_step< 59, 29,  99>(h4 + 4*hstep, OSL(4), xt, y0, wp, gprev);
    scale_step<117, 58, 165>(h4 + 5*hstep, OSL(5), xt, y0, wp, gprev);
    float4* o6 = OSL(6);
#pragma unroll
    for (int j = 0; j < 8; ++j) o6[(size_t)(y0 + j) * (WW/4) + xt] = gprev[j];
#undef OSL
}

// ---------------- single-scale vblur (+optional diff) (fallback paths) ----------------------
template<int KS, int PD, int WOP>
__global__ __launch_bounds__(128, 3) void vdiff1_kernel(const float* hsrc, int hslot,
                                                        const float* gsrc, int gslot,
                                                        float* out, int dslot, int goutslot,
                                                        WP wp)
{
    const int xt = threadIdx.x;
    const int y0 = blockIdx.y * 8;
    const int bc = blockIdx.z;
    const int b = bc / CH, c = bc - b * CH;
    const size_t contig = (size_t)bc * (HWX/4);
    float4* out4 = (float4*)out;
    auto voff4 = [&](int slot) -> size_t {
        return ((size_t)((b * NSLOT + slot) * CH) + c) * (HWX/4);
    };
    const float4* h4 = (const float4*)hsrc + (hslot < 0 ? contig : voff4(hslot));
    float4 acc[8];
    vblur8<KS, PD, WOP>(h4, xt, y0, wp, acc);
    if (gsrc) {
        const float4* g4 = (const float4*)gsrc + (gslot < 0 ? contig : voff4(gslot));
        float4* od = out4 + voff4(dslot);
#pragma unroll
        for (int j = 0; j < 8; ++j) {
            float4 pv = g4[(size_t)(y0 + j) * (WW/4) + xt];
            float4 g  = acc[j];
            od[(size_t)(y0 + j) * (WW/4) + xt] =
                make_float4(g.x - pv.x, g.y - pv.y, g.z - pv.z, g.w - pv.w);
        }
    }
    float4* og = out4 + voff4(goutslot);
#pragma unroll
    for (int j = 0; j < 8; ++j) og[(size_t)(y0 + j) * (WW/4) + xt] = acc[j];
}

// ---------------- round-0 style diff (ultra-fallback) ---------------------------------------
__global__ __launch_bounds__(256) void diff4_kernel(const float4* __restrict__ img4,
                                                    float4* out4)
{
    const size_t CHW4 = (size_t)CH * HWX / 4;
    size_t idx = (size_t)blockIdx.x * 256 + threadIdx.x;
    if (idx >= (size_t)BATCH * CHW4) return;
    const size_t b = idx / CHW4, rem = idx - b * CHW4;
    float4 prev = img4[idx];
    float4* ob = out4 + b * (size_t)NSLOT * CHW4;
    float4 g[6];
#pragma unroll
    for (int s = 0; s < 6; ++s) g[s] = ob[(size_t)(s + 1) * CHW4 + rem];
    ob[rem] = make_float4(g[0].x - prev.x, g[0].y - prev.y, g[0].z - prev.z, g[0].w - prev.w);
#pragma unroll
    for (int s = 1; s < 6; ++s)
        ob[(size_t)s * CHW4 + rem] = make_float4(g[s].x - g[s-1].x, g[s].y - g[s-1].y,
                                                 g[s].z - g[s-1].z, g[s].w - g[s-1].w);
}

// ---------------- host ----------------------------------------------------------------------
static void fill_wp(WP& wp)
{
    const double sig[6] = {0.6, 1.2, 2.4, 4.8, 9.6, 19.2};
    const int ks[6]  = {7, 9, 17, 31, 59, 117};
    const int wop[6] = {7, 21, 37, 61, 99, 165};
    for (int i = 0; i < NWP; ++i) wp.w[i] = 0.f;
    for (int s = 0; s < 6; ++s) {
        const int k = ks[s], p = k / 2;
        double sum = 0.0;
        for (int t = 0; t < k; ++t) {
            const double ax = (double)(t - p);
            const double v = std::exp(-(ax * ax) / (2.0 * sig[s] * sig[s]));
            wp.w[wop[s] + t] = (float)v;
            sum += v;
        }
        const float inv = (float)(1.0 / sum);
        for (int t = 0; t < k; ++t) wp.w[wop[s] + t] *= inv;
    }
}

extern "C" void kernel_launch(void* const* d_in, const int* in_sizes, int n_in,
                              void* d_out, int out_size, void* d_ws, size_t ws_size,
                              hipStream_t stream) {
    const float* img = (const float*)d_in[0];
    float* out = (float*)d_out;
    float* wsf = (float*)d_ws;

    WP wp;
    fill_wp(wp);

    const dim3 bh(128, 2), gh(1, HH / 2, BATCH * CH);
    const dim3 bv(128, 1), gv(1, HH / 8, BATCH * CH);

    if (ws_size >= 6 * NPIX * sizeof(float)) {
        // PATH1: fully fused — 2 launches
        hipLaunchKernelGGL(hpass6_kernel, gh, bh, 0, stream, img, wsf, wp);
        hipLaunchKernelGGL(vdiff6_kernel, gv, bv, 0, stream, wsf, img, out, wp);
    } else if (ws_size >= NPIX * sizeof(float)) {
        // PATH2: per-scale, g ping-pong through out slot 6, diffs fused
#define P2(S, KS, PD, WOP)                                                                 \
        hipLaunchKernelGGL((hpass1_kernel<KS, PD, WOP>), gh, bh, 0, stream,                \
                           img, wsf, -1, wp);                                              \
        hipLaunchKernelGGL((vdiff1_kernel<KS, PD, WOP>), gv, bv, 0, stream,                \
                           wsf, -1, (S == 0) ? img : (const float*)out,                    \
                           (S == 0) ? -1 : 6, out, S, 6, wp);
        P2(0,   7,  3,   7)
        P2(1,   9,  4,  21)
        P2(2,  17,  8,  37)
        P2(3,  31, 15,  61)
        P2(4,  59, 29,  99)
        P2(5, 117, 58, 165)
#undef P2
    } else {
        // PATH3: round-0 structure (slot0 scratch) with templated fast kernels
#define P3(S, KS, PD, WOP)                                                                 \
        hipLaunchKernelGGL((hpass1_kernel<KS, PD, WOP>), gh, bh, 0, stream,                \
                           img, out, 0, wp);                                               \
        hipLaunchKernelGGL((vdiff1_kernel<KS, PD, WOP>), gv, bv, 0, stream,                \
                           (const float*)out, 0, (const float*)nullptr, -1,                \
                           out, -1, S + 1, wp);
        P3(0,   7,  3,   7)
        P3(1,   9,  4,  21)
        P3(2,  17,  8,  37)
        P3(3,  31, 15,  61)
        P3(4,  59, 29,  99)
        P3(5, 117, 58, 165)
#undef P3
        const size_t n4 = NPIX / 4;
        dim3 gd((unsigned)((n4 + 255) / 256));
        hipLaunchKernelGGL(diff4_kernel, gd, dim3(256), 0, stream,
                           (const float4*)img, (float4*)out);
    }
}

// Round 3
// 390.693 us; speedup vs baseline: 2.6375x; 1.0015x over previous
//
#include <hip/hip_runtime.h>
#include <cmath>
#include <cstddef>

#define BATCH 8
#define CH    3
#define HH    512
#define WW    512
#define NSLOT 7
#define HWX   (HH*WW)

// scales: KS {7,9,17,31,59,117}, P=KS/2
// vpass kernarg weight layout: [16 z][KS][... ] offsets WOPV {16,39,64,97,144,219}, size 352
#define NWP 352
struct WP { float w[NWP]; };

__device__ __host__ __forceinline__ int refl(int i, int n) {
    i = i < 0 ? -i : i;
    return i >= n ? 2 * n - 2 - i : i;
}

// ---------------- compile-time Gaussian weights (literal-folded in hdiff6) -----------------
template<int KS> struct WArr { float w[KS + 16]; };   // real taps at [8, 8+KS), zeros elsewhere

constexpr double cexp_(double x) {           // e^x for x in [-13, 0]
    double r = x / 64.0, term = 1.0, s = 1.0;
    for (int i = 1; i < 26; ++i) { term *= r / i; s += term; }
    for (int j = 0; j < 6; ++j) s *= s;      // s = (e^{x/64})^64
    return s;
}

template<int KS>
constexpr WArr<KS> make_w(double sg) {
    WArr<KS> a{};
    double tmp[KS] = {};
    double sum = 0.0;
    for (int t = 0; t < KS; ++t) {
        const double ax = (double)(t - KS / 2);
        tmp[t] = cexp_(-(ax * ax) / (2.0 * sg * sg));
        sum += tmp[t];
    }
    for (int i = 0; i < KS + 16; ++i) a.w[i] = 0.0f;
    for (int t = 0; t < KS; ++t) a.w[8 + t] = (float)(tmp[t] / sum);
    return a;
}

__device__ constexpr WArr<7>   CW0 = make_w<7>(0.6);
__device__ constexpr WArr<9>   CW1 = make_w<9>(1.2);
__device__ constexpr WArr<17>  CW2 = make_w<17>(2.4);
__device__ constexpr WArr<31>  CW3 = make_w<31>(4.8);
__device__ constexpr WArr<59>  CW4 = make_w<59>(9.6);
__device__ constexpr WArr<117> CW5 = make_w<117>(19.2);

// ---------------- vertical blur: 16 rows x float4 per thread, img -> out slot s+1 ----------
template<int KS, int PD, int WOP>
__device__ __forceinline__ void vpass16(const float4* __restrict__ img4,
                                        float4* __restrict__ dst,
                                        int xt, int y0, const WP& wp)
{
    float4 acc[16];
#pragma unroll
    for (int j = 0; j < 16; ++j) acc[j] = make_float4(0.f, 0.f, 0.f, 0.f);
#pragma unroll 2
    for (int t = 0; t < KS + 15; ++t) {
        const int yi = refl(y0 - PD + t, HH);
        const float4 v = img4[(size_t)yi * (WW / 4) + xt];
#pragma unroll
        for (int j = 0; j < 16; ++j) {
            const float wt = wp.w[WOP + t - j];   // zero-padded both sides
            acc[j].x = fmaf(wt, v.x, acc[j].x);
            acc[j].y = fmaf(wt, v.y, acc[j].y);
            acc[j].z = fmaf(wt, v.z, acc[j].z);
            acc[j].w = fmaf(wt, v.w, acc[j].w);
        }
    }
#pragma unroll
    for (int j = 0; j < 16; ++j) dst[(size_t)(y0 + j) * (WW / 4) + xt] = acc[j];
}

__global__ __launch_bounds__(128) void vpass6_kernel(const float* __restrict__ img,
                                                     float* __restrict__ out, WP wp)
{
    const int s  = blockIdx.x;
    const int xt = threadIdx.x;              // 0..127 (float4 col)
    const int y0 = blockIdx.y * 16;
    const int bc = blockIdx.z;
    const int b = bc / CH, c = bc - b * CH;
    const float4* img4 = (const float4*)img + (size_t)bc * (HWX / 4);
    float4* dst = (float4*)out + ((size_t)((b * NSLOT + s + 1) * CH) + c) * (HWX / 4);
    switch (s) {
        case 0: vpass16<  7,  3,  16>(img4, dst, xt, y0, wp); break;
        case 1: vpass16<  9,  4,  39>(img4, dst, xt, y0, wp); break;
        case 2: vpass16< 17,  8,  64>(img4, dst, xt, y0, wp); break;
        case 3: vpass16< 31, 15,  97>(img4, dst, xt, y0, wp); break;
        case 4: vpass16< 59, 29, 144>(img4, dst, xt, y0, wp); break;
        default:vpass16<117, 58, 219>(img4, dst, xt, y0, wp); break;
    }
}

// ---------------- horizontal blur: 4 px/thread, b128 rolling window, literal weights -------
// lrow has left pad P (lrow[i] = v[i-P]); output px 4*xt+j = sum_t W[t]*lrow[4*xt+j+t]
template<int KS>
__device__ __forceinline__ float4 hblur4c(const float* __restrict__ lrow, int xt,
                                          const WArr<KS>& W)
{
    constexpr int NT = (KS + 3) & ~3;
    const float4* l4 = (const float4*)lrow;
    float cb[16];
    {
        float4 t0 = l4[xt + 0];
        cb[0] = t0.x; cb[1] = t0.y; cb[2] = t0.z; cb[3] = t0.w;
        float4 t1 = l4[xt + 1];
        cb[4] = t1.x; cb[5] = t1.y; cb[6] = t1.z; cb[7] = t1.w;
    }
    float a[4] = {0.f, 0.f, 0.f, 0.f};
#pragma unroll
    for (int tb = 0; tb < NT; tb += 4) {
        const int ls = ((tb >> 2) + 2) & 3;
        float4 tn = l4[xt + (tb >> 2) + 2];          // overshoot covered by LEN pad
        cb[ls * 4 + 0] = tn.x; cb[ls * 4 + 1] = tn.y;
        cb[ls * 4 + 2] = tn.z; cb[ls * 4 + 3] = tn.w;
#pragma unroll
        for (int tt = 0; tt < 4; ++tt) {
            const float wt = W.w[8 + tb + tt];       // compile-time constant
#pragma unroll
            for (int j = 0; j < 4; ++j) {
                const int q    = tt + j;             // 0..6
                const int slot = ((tb >> 2) + (q >> 2)) & 3;
                a[j] = fmaf(wt, cb[slot * 4 + (q & 3)], a[j]);
            }
        }
    }
    return make_float4(a[0], a[1], a[2], a[3]);
}

// ---------------- fused h-pass + DoG diff, in-place on out ---------------------------------
// LDS row-group layout (floats): img[0,512) then per scale [OFF, OFF+LEN) with left pad P
// LEN = NT + 516 (covers rolling-window overshoot; all staged values finite via refl)
// s:      0     1     2     3     4     5
// OFF:  512  1036  1564  2100  2648  3224
// LEN:  524   528   536   548   576   636
#define LDSROW 3860

template<int OFF, int LEN, int PD>
__device__ __forceinline__ void stage_row(float* __restrict__ L,
                                          const float* __restrict__ g, int xt)
{
    for (int i = xt; i < LEN; i += 128) L[OFF + i] = g[refl(i - PD, WW)];
}

__device__ __forceinline__ float4 f4sub(float4 a, float4 b) {
    return make_float4(a.x - b.x, a.y - b.y, a.z - b.z, a.w - b.w);
}

__global__ __launch_bounds__(256) void hdiff6_kernel(const float* __restrict__ img,
                                                     float* __restrict__ out)
{
    __shared__ __align__(16) float lds[2][LDSROW];
    const int xt = threadIdx.x;              // 0..127
    const int r  = threadIdx.y;              // 0..1
    const int y  = blockIdx.y * 2 + r;
    const int bc = blockIdx.z;
    const int b = bc / CH, c = bc - b * CH;
    float* L = lds[r];

    // stage img row (exact 512 floats = 128 float4)
    const float* irow = img + ((size_t)bc * HH + y) * WW;
    ((float4*)L)[xt] = ((const float4*)irow)[xt];

    // stage the 6 v-blurred rows from out slots 1..6 (with reflect x-halo)
    const size_t rowoff = (size_t)y * WW;
    const float* g1 = out + ((size_t)((b * NSLOT + 1) * CH) + c) * HWX + rowoff;
    const float* g2 = out + ((size_t)((b * NSLOT + 2) * CH) + c) * HWX + rowoff;
    const float* g3 = out + ((size_t)((b * NSLOT + 3) * CH) + c) * HWX + rowoff;
    const float* g4 = out + ((size_t)((b * NSLOT + 4) * CH) + c) * HWX + rowoff;
    const float* g5 = out + ((size_t)((b * NSLOT + 5) * CH) + c) * HWX + rowoff;
    const float* g6 = out + ((size_t)((b * NSLOT + 6) * CH) + c) * HWX + rowoff;
    stage_row< 512, 524,  3>(L, g1, xt);
    stage_row<1036, 528,  4>(L, g2, xt);
    stage_row<1564, 536,  8>(L, g3, xt);
    stage_row<2100, 548, 15>(L, g4, xt);
    stage_row<2648, 576, 29>(L, g5, xt);
    stage_row<3224, 636, 58>(L, g6, xt);
    __syncthreads();

    float4* out4 = (float4*)out;
    const size_t pbase = (size_t)y * (WW / 4) + xt;
#define OSL(s) (out4 + ((size_t)((b * NSLOT + (s)) * CH) + c) * (HWX / 4) + pbase)

    float4 gp = ((const float4*)L)[xt];      // g0 = img
    float4 g;
    g = hblur4c<  7>(L +  512, xt, CW0); *OSL(0) = f4sub(g, gp); gp = g;
    g = hblur4c<  9>(L + 1036, xt, CW1); *OSL(1) = f4sub(g, gp); gp = g;
    g = hblur4c< 17>(L + 1564, xt, CW2); *OSL(2) = f4sub(g, gp); gp = g;
    g = hblur4c< 31>(L + 2100, xt, CW3); *OSL(3) = f4sub(g, gp); gp = g;
    g = hblur4c< 59>(L + 2648, xt, CW4); *OSL(4) = f4sub(g, gp); gp = g;
    g = hblur4c<117>(L + 3224, xt, CW5); *OSL(5) = f4sub(g, gp);
    *OSL(6) = g;
#undef OSL
}

// ---------------- host ----------------------------------------------------------------------
static void fill_wp(WP& wp)
{
    const double sig[6] = {0.6, 1.2, 2.4, 4.8, 9.6, 19.2};
    const int ks[6]  = {7, 9, 17, 31, 59, 117};
    const int wop[6] = {16, 39, 64, 97, 144, 219};
    for (int i = 0; i < NWP; ++i) wp.w[i] = 0.f;
    for (int s = 0; s < 6; ++s) {
        const int k = ks[s], p = k / 2;
        double sum = 0.0;
        for (int t = 0; t < k; ++t) {
            const double ax = (double)(t - p);
            const double v = std::exp(-(ax * ax) / (2.0 * sig[s] * sig[s]));
            wp.w[wop[s] + t] = (float)v;
            sum += v;
        }
        const float inv = (float)(1.0 / sum);
        for (int t = 0; t < k; ++t) wp.w[wop[s] + t] *= inv;
    }
}

extern "C" void kernel_launch(void* const* d_in, const int* in_sizes, int n_in,
                              void* d_out, int out_size, void* d_ws, size_t ws_size,
                              hipStream_t stream) {
    const float* img = (const float*)d_in[0];
    float* out = (float*)d_out;

    WP wp;
    fill_wp(wp);

    // pass 1: vertical blur img -> out slots 1..6 (no workspace needed)
    const dim3 bv(128, 1), gv(6, HH / 16, BATCH * CH);
    hipLaunchKernelGGL(vpass6_kernel, gv, bv, 0, stream, img, out, wp);

    // pass 2: horizontal blur + DoG diff chain, in-place on out
    const dim3 bh(128, 2), gh(1, HH / 2, BATCH * CH);
    hipLaunchKernelGGL(hdiff6_kernel, gh, bh, 0, stream, img, out);
}